// Round 1
// baseline (271.397 us; speedup 1.0000x reference)
//
#include <hip/hip_runtime.h>
#include <math.h>

// Problem constants (reference: B=32, P=256, D=64, T=4096, SCALE=1)
#define Bb 32
#define Pp 256
#define Dd 64
#define Tt 4096

// kernel1: one wave per (batch, 64-task chunk). 64 chunks/batch -> 2048 waves.
// grid: 512 blocks x 256 threads; b = blk>>4 (uniform per block), chunk = (blk&15)*4 + wid.
// No LDS, no barriers: waves are fully independent.
// ws layout: float triple (m, s, v) at [((b*P + p)*64 + chunk)*3]  -> 6.3 MB total.
__global__ __launch_bounds__(256) void k_scan(const float* __restrict__ data,
                                              const float* __restrict__ targets,
                                              const float* __restrict__ task_pool,
                                              float* __restrict__ ws) {
  const int b     = blockIdx.x >> 4;          // 16 blocks per batch
  const int wid   = threadIdx.x >> 6;
  const int lane  = threadIdx.x & 63;
  const int chunk = ((blockIdx.x & 15) << 2) | wid;   // 0..63
  const int t     = (chunk << 6) | lane;              // this lane's task

  // W column for task t lives in 64 VGPRs for the whole kernel.
  float w[Dd];
#pragma unroll
  for (int d = 0; d < Dd; d += 4) {
    const float4 r = *(const float4*)(task_pool + (size_t)t * Dd + d);
    w[d] = r.x; w[d + 1] = r.y; w[d + 2] = r.z; w[d + 3] = r.w;
  }

  const float* __restrict__ drow = data + (size_t)b * (Pp * Dd);  // wave-uniform base
  const float* __restrict__ tgt  = targets + b * Pp;
  float* __restrict__ wsb        = ws + (size_t)b * (Pp * 64 * 3);

  float c = 0.f;  // cumulative score (loglik prefix) for this lane's task
  for (int p = 0; p < Pp; ++p) {
    // pred = data[b,p,:] . W[:,t]  — data row address is wave-uniform -> s_load
    float pred = 0.f;
#pragma unroll
    for (int d = 0; d < Dd; d += 4) {
      const float4 r = *(const float4*)(drow + p * Dd + d);
      pred = fmaf(r.x, w[d],     pred);
      pred = fmaf(r.y, w[d + 1], pred);
      pred = fmaf(r.z, w[d + 2], pred);
      pred = fmaf(r.w, w[d + 3], pred);
    }

    // posterior over this chunk uses c (= prefix through p-1; p=0 -> uniform)
    float m = c;
#pragma unroll
    for (int off = 32; off; off >>= 1) m = fmaxf(m, __shfl_xor(m, off, 64));
    const float e = __expf(c - m);   // <= 1, no overflow (scores <= 0)
    float s = e, v = e * pred;
#pragma unroll
    for (int off = 32; off; off >>= 1) {
      s += __shfl_xor(s, off, 64);
      v += __shfl_xor(v, off, 64);
    }
    if (lane == 0) {
      float* o = wsb + ((size_t)p * 64 + chunk) * 3;
      o[0] = m; o[1] = s; o[2] = v;
    }

    // score update AFTER emitting the prefix posterior (log_norm const drops out)
    const float err = tgt[p] - pred;
    c = fmaf(-0.5f * err, err, c);
  }
}

// kernel2: one wave per (b,p); exact merge of the 64 chunk triples.
// value represented by a triple is e^m * (s, v); merge with global shift M.
__global__ __launch_bounds__(256) void k_merge(const float* __restrict__ ws,
                                               float* __restrict__ out) {
  const int gt   = blockIdx.x * 256 + threadIdx.x;
  const int bp   = gt >> 6;   // b*P + p
  const int lane = gt & 63;   // chunk id
  const float* o = ws + (size_t)(bp * 64 + lane) * 3;
  const float m = o[0], s = o[1], v = o[2];
  float M = m;
#pragma unroll
  for (int off = 32; off; off >>= 1) M = fmaxf(M, __shfl_xor(M, off, 64));
  const float f = __expf(m - M);
  float S = f * s, V = f * v;
#pragma unroll
  for (int off = 32; off; off >>= 1) {
    S += __shfl_xor(S, off, 64);
    V += __shfl_xor(V, off, 64);
  }
  if (lane == 0) out[bp] = V / S;
}

extern "C" void kernel_launch(void* const* d_in, const int* in_sizes, int n_in,
                              void* d_out, int out_size, void* d_ws, size_t ws_size,
                              hipStream_t stream) {
  const float* data      = (const float*)d_in[0];
  const float* targets   = (const float*)d_in[1];
  const float* task_pool = (const float*)d_in[2];
  float* out = (float*)d_out;
  float* ws  = (float*)d_ws;   // needs 32*256*64*3*4 B = 6.3 MB

  k_scan<<<dim3(512), dim3(256), 0, stream>>>(data, targets, task_pool, ws);
  k_merge<<<dim3((Bb * Pp * 64) / 256), dim3(256), 0, stream>>>(ws, out);
}